// Round 7
// baseline (97.729 us; speedup 1.0000x reference)
//
#include <hip/hip_runtime.h>
#include <stdint.h>

#define NN 4096
#define NC 7
#define SIG1 0.7310585786300049f
#define PER_C 0.001f
#define ISTRIDE 2560            // >= worst-case M, multiple of 128
#define NTILE2 (ISTRIDE / 128)  // 20
#define NPB2 (NTILE2 * NTILE2)  // 400 tile blocks
#define CLRB 256
#define PREPC_GRID (17 + CLRB)

// ---------------- ws layout ----------------
#define BITS_OFF   0                          // u64 bits[4096][64] = 2MB (dense fallback only)
#define DEG_OFF    (2*1024*1024)              // int deg[4096]
#define DIAGP_OFF  (DEG_OFF   + NN*4)         // float diagP[4096]
#define SELF_OFF   (DIAGP_OFF + NN*4)         // int selfq[4096] (dense fallback only)
#define MIDX_OFF   (SELF_OFF  + NN*4)         // int midx[4096] (compacted masked ids)
#define MLAB_OFF   (MIDX_OFF  + NN*4)         // int mlab[4096]
#define ACC_OFF    (MLAB_OFF  + NN*4)         // 128 words; see index map below
#define MINV_OFF   (ACC_OFF   + 512)          // int minv[4096]
#define MASKW_OFF  (MINV_OFF  + NN*4)         // u64 maskw[64] (PERMUTED layout)
#define INTER_OFF  (MASKW_OFF + 512)          // u8 inter[ISTRIDE][ISTRIDE]; bit7 = adj[p,q]&~adj[q,q]
#define INTER_BYTES ((size_t)ISTRIDE * (size_t)ISTRIDE)
#define INTER_U4   ((int)(INTER_BYTES / 16))  // 409600 uint4s
#define PT_OFF     (INTER_OFF + INTER_BYTES)  // float partialsT[53][NPB2]
#define PT_BYTES   ((size_t)53 * NPB2 * 4)
#define WS_NEED    ((size_t)PT_OFF + PT_BYTES)
// acc word indices: 0..48 T, 49..55 Ncnt(int), 56..59 masks(uint),
//                   60 M(int), 61..76 ce_part[16]

// Bit permutation: column c lives in word W(c)=4*(c>>8)+(c&3), bit b(c)=(c>>2)&63.
// Inverse: (W,b) -> c = 256*(W>>2) + 4*b + (W&3).
// AND/popcount between rows is permutation-invariant.

// Lessons encoded (r1/r2/r4/r5/r6):
//  - global atomics from ~1k blocks to 5 cachelines = ~40us storm -> per-block partials.
//  - rocclr fillBuffer (hipMemsetAsync) = 40us at 8% occupancy -> clear with our own blocks.
//  - __threadfence grid handoff on gfx950 = per-XCD L2 writeback, 258us -> the kernel
//    launch boundary IS the cheap fence.
//  - 1-block reduce of 339KB cross-XCD partials = latency-bound -> 53-block reduce.
//  - scatter fused into the HBM-bound build hides its cost; requires (a) inter8 cleared
//    in an EARLIER kernel (6.5MB = ~1.5us, cheap) and (b) no cross-row selfq read: the
//    bit7 term is written by the COLUMN-owning wave (knows its own diagonal in regs).

// ---------------- sparse path ----------------

// k_prepclear: blocks 0..15 CE partials + diagP; block 16: acc zero, compact scan,
// Ncnt, M, minv, permuted maskw; blocks 17..272: clear inter8.
__global__ void k_prepclear(const float* __restrict__ preds, const int* __restrict__ labels,
                            const int* __restrict__ mask, float* __restrict__ diagP,
                            int* __restrict__ midx, int* __restrict__ mlab,
                            float* __restrict__ acc, int* __restrict__ minv,
                            unsigned long long* __restrict__ maskw,
                            uint4* __restrict__ inter_clear) {
    int t = threadIdx.x;
    int b = blockIdx.x;
    if (b >= 17) {
        int cb = b - 17;                       // 0..CLRB-1
        for (int i = cb * 256 + t; i < INTER_U4; i += CLRB * 256)
            inter_clear[i] = make_uint4(0u, 0u, 0u, 0u);
        return;
    }
    if (b == 16) {
        __shared__ int cnts[256];
        __shared__ int sN[NC];
        if (t < 49) acc[t] = 0.f;                 // T
        if (t >= 56 && t < 60) acc[t] = 0.f;      // masks
        if (t < NC) sN[t] = 0;
        for (int i = t; i < NN; i += 256) { midx[i] = 0; mlab[i] = 0; }
        if (t < 64) {
            // permuted: maskw[W] bit b = mask[256*(W>>2) + 4*b + (W&3)]
            int base = 256 * (t >> 2) + (t & 3);
            unsigned long long w = 0ull;
            for (int bb = 0; bb < 64; bb++)
                w |= ((unsigned long long)(mask[base + 4 * bb] != 0)) << bb;
            maskw[t] = w;
        }

        int base_n = t * 16;
        int my[16];
        int c = 0;
        #pragma unroll
        for (int k = 0; k < 16; k++) { my[k] = mask[base_n + k]; c += (my[k] != 0); }
        cnts[t] = c;
        __syncthreads();
        for (int s = 1; s < 256; s <<= 1) {
            int v = (t >= s) ? cnts[t - s] : 0;
            __syncthreads();
            cnts[t] += v;
            __syncthreads();
        }
        int pos = cnts[t] - c;  // exclusive prefix
        #pragma unroll
        for (int k = 0; k < 16; k++) {
            if (my[k]) {
                int node = base_n + k;
                int l = labels[node];
                midx[pos] = node;
                mlab[pos] = l;
                minv[node] = pos;
                atomicAdd(&sN[l], 1);
                pos++;
            }
        }
        __syncthreads();
        if (t < NC) ((int*)acc)[49 + t] = sN[t];
        if (t == 255) ((int*)acc)[60] = cnts[255];   // M
    } else {
        int p = b * 256 + t;
        int l = labels[p];
        const float* pr = preds + p * NC;
        float x[NC];
        #pragma unroll
        for (int c = 0; c < NC; c++) x[c] = pr[c];
        float mx = x[0];
        #pragma unroll
        for (int c = 1; c < NC; c++) mx = fmaxf(mx, x[c]);
        float s = 0.f;
        #pragma unroll
        for (int c = 0; c < NC; c++) s += __expf(x[c] - mx);
        float lse = mx + logf(s);
        float dp = x[l];
        diagP[p] = dp;

        __shared__ float red[256];
        red[t] = lse - dp;
        __syncthreads();
        for (int st = 128; st > 0; st >>= 1) {
            if (t < st) red[t] += red[t + st];
            __syncthreads();
        }
        if (t == 0) acc[61 + b] = red[0];
    }
}

// k_build_scatter: one wave per row k. Streams the 64MB adj row (int4, permuted
// ballots), writes deg, then (row still in regs) scatters:
//  - inter[i][j] += 1 for each pair (i,j) of MASKED neighbors of k (low 7 bits)
//  - if k masked AND adj[k,k]==0: bit7 of inter[minv[p]][minv[k]] for each masked
//    neighbor p (column-flip of adj[p,q]&~self_q: writer owns its own diagonal).
// All scatter work is wave-local (maskw/minv from k_prepclear across the launch
// boundary); VALU tail hides under the HBM-bound read. No bits/selfq writes.
__global__ void k_build_scatter(const int* __restrict__ adj,
                                int* __restrict__ deg,
                                const unsigned long long* __restrict__ maskw,
                                const int* __restrict__ minv,
                                unsigned int* __restrict__ inter32) {
    __shared__ unsigned short L[4][80];
    __shared__ int sn[4];
    int w = threadIdx.x >> 6, lane = threadIdx.x & 63;
    int row = blockIdx.x * 4 + w;
    const int4* a4 = (const int4*)(adj + (size_t)row * NN);
    unsigned long long myw = 0ull;
    int sel = lane >> 2, sc = lane & 3;
    #pragma unroll
    for (int w4 = 0; w4 < 16; w4++) {
        int4 v = a4[w4 * 64 + lane];   // cols 256*w4 + 4*lane + {0..3}; 1KB/instr coalesced
        unsigned long long m0 = __ballot(v.x != 0);
        unsigned long long m1 = __ballot(v.y != 0);
        unsigned long long m2 = __ballot(v.z != 0);
        unsigned long long m3 = __ballot(v.w != 0);
        if (sel == w4) myw = (sc & 2) ? ((sc & 1) ? m3 : m2) : ((sc & 1) ? m1 : m0);
    }
    int d = __popcll(myw);
    #pragma unroll
    for (int o = 32; o > 0; o >>= 1) d += __shfl_down(d, o);
    if (lane == 0) deg[row] = d;

    // ---- fused scatter ----
    unsigned long long bw = myw & maskw[lane];
    int c = __popcll(bw);
    int inc = c;
    #pragma unroll
    for (int o = 1; o < 64; o <<= 1) { int v = __shfl_up(inc, o); if (lane >= o) inc += v; }
    int pos = inc - c;                 // exclusive prefix
    unsigned long long tmp = bw;
    while (tmp) {
        int bb = __ffsll(tmp) - 1;
        tmp &= tmp - 1;
        int node = 256 * (lane >> 2) + 4 * bb + (lane & 3);   // permuted decode
        if (pos < 80) L[w][pos] = (unsigned short)minv[node];
        pos++;
    }
    if (lane == 63) sn[w] = (inc < 80) ? inc : 80;
    __syncthreads();

    int n = sn[w];
    for (int idx = lane; idx < n * n; idx += 64) {
        int i = idx / n, j = idx - i * n;
        unsigned int a = (unsigned int)L[w][i] * ISTRIDE + (unsigned int)L[w][j];
        atomicAdd(&inter32[a >> 2], 1u << ((a & 3) * 8));
    }

    // column-flip bit7: row k (= column q) masked and own diagonal == 0
    int Wk = 4 * (row >> 8) + (row & 3);
    int km = (int)((maskw[Wk] >> ((row >> 2) & 63)) & 1ull);
    if (km) {
        unsigned long long dw = __shfl(myw, Wk);
        int selfk = (int)((dw >> ((row >> 2) & 63)) & 1ull);
        if (!selfk) {
            int kc = minv[row];
            for (int j = lane; j < n; j += 64) {
                unsigned int a = (unsigned int)L[w][j] * ISTRIDE + (unsigned int)kc;
                atomicOr(&inter32[a >> 2], 0x80u << ((a & 3) * 8));
            }
        }
    }
}

// Pair epilogue: 128x128 tile, 8x8 per thread. One coalesced 8B read of inter8 per
// p-row covers 8 pairs (low7=inter, bit7=adj&~self). NO global atomics, NO fences:
// each block writes its 49 T partials + 4 mask words to partialsT[53][NPB2].
__launch_bounds__(256)
__global__ void k_pairs2(const float* __restrict__ preds,
                         const int* __restrict__ deg,
                         const float* __restrict__ diagP,
                         const int* __restrict__ midx,
                         const int* __restrict__ mlab,
                         const int* __restrict__ Mptr,
                         const unsigned char* __restrict__ inter8,
                         float* __restrict__ partialsT) {
    __shared__ float predsQ[NC * 128];   // transposed [c][r]
    __shared__ float diagPp[128];
    __shared__ int labP[128], labQ[128], degP[128];
    __shared__ float T_lds[49];
    __shared__ unsigned int s_m[4];

    int M = Mptr[0];
    int p0 = blockIdx.y * 128, q0 = blockIdx.x * 128;
    int bl = blockIdx.y * gridDim.x + blockIdx.x;   // 0..NPB2-1
    int t = threadIdx.x;

    if (p0 >= M || q0 >= M) {
        if (t < 53) partialsT[t * NPB2 + bl] = 0.f;
        return;
    }

    if (t < 49) T_lds[t] = 0.f;
    if (t >= 49 && t < 53) s_m[t - 49] = 0u;
    if (t < 128) {
        int pi = midx[p0 + t];
        diagPp[t] = diagP[pi];
        degP[t] = deg[pi];
        labP[t] = mlab[p0 + t];
        labQ[t] = mlab[q0 + t];
    }
    for (int idx = t; idx < NC * 128; idx += 256) {
        int c = idx >> 7, r = idx & 127;
        predsQ[idx] = preds[midx[q0 + r] * NC + c];
    }
    __syncthreads();

    int tx = t & 15, ty = t >> 4;
    int lane = t & 63;
    unsigned long long lsub = 0ull, linter = 0ull;

    #pragma unroll
    for (int i = 0; i < 8; i++) {
        int pl = 8 * ty + i;
        if ((p0 + pl) >= M) continue;
        int lp_ = labP[pl], dgp = degP[pl];
        float dPp = diagPp[pl];
        uint2 iw2 = *(const uint2*)&inter8[(size_t)(p0 + pl) * ISTRIDE + q0 + 8 * tx];
        #pragma unroll
        for (int j = 0; j < 8; j++) {
            int ql = 8 * tx + j;
            if ((q0 + ql) >= M) continue;
            unsigned int u = ((j < 4) ? (iw2.x >> (8 * j)) : (iw2.y >> (8 * (j - 4)))) & 255u;
            int inter = (int)(u & 127u);
            int bitterm = (int)(u >> 7);
            int sub = dgp - inter - bitterm;
            int lq_ = labQ[ql];
            int bidx = lp_ * 7 + lq_;
            if (sub > 0)   lsub   |= 1ull << bidx;
            if (inter > 0) linter |= 1ull << bidx;
            if (lp_ != lq_) {
                float arg = (1.f + SIG1 * (float)sub) / (1.f + SIG1 * (float)inter);
                float v = 1.f / (1.f + __expf(arg));             // 1 - sigmoid(arg)
                float E = __expf(predsQ[lp_ * 128 + ql] - dPp);  // exp(G - diagP)
                atomicAdd(&T_lds[bidx], E * v);
            }
        }
    }
    // wave-level OR reduce, then 4 LDS atomics per wave
    #pragma unroll
    for (int o = 32; o > 0; o >>= 1) {
        lsub   |= __shfl_xor(lsub, o);
        linter |= __shfl_xor(linter, o);
    }
    if (lane == 0) {
        atomicOr(&s_m[0], (unsigned int)(lsub & 0xffffffffull));
        atomicOr(&s_m[1], (unsigned int)(lsub >> 32));
        atomicOr(&s_m[2], (unsigned int)(linter & 0xffffffffull));
        atomicOr(&s_m[3], (unsigned int)(linter >> 32));
    }
    __syncthreads();

    if (t < 49) partialsT[t * NPB2 + bl] = T_lds[t];
    if (t >= 49 && t < 53) partialsT[t * NPB2 + bl] = __uint_as_float(s_m[t - 49]);
}

// Reduce partialsT[53][NPB2] -> acc. 53 blocks (parallel; 1-block variant was
// latency-bound, r5). j<49: float sum; j>=49: OR into masks.
__global__ void k_reduce(const float* __restrict__ pt, float* __restrict__ acc) {
    int j = blockIdx.x;      // 0..52
    int t = threadIdx.x;     // 256
    const float* row = pt + (size_t)j * NPB2;
    if (j < 49) {
        __shared__ float sf[256];
        float s = 0.f;
        for (int i = t; i < NPB2; i += 256) s += row[i];
        sf[t] = s;
        __syncthreads();
        for (int st = 128; st > 0; st >>= 1) { if (t < st) sf[t] += sf[t + st]; __syncthreads(); }
        if (t == 0) acc[j] = sf[0];
    } else {
        __shared__ unsigned int su[256];
        unsigned int m = 0u;
        for (int i = t; i < NPB2; i += 256) m |= __float_as_uint(row[i]);
        su[t] = m;
        __syncthreads();
        for (int st = 128; st > 0; st >>= 1) { if (t < st) su[t] |= su[t + st]; __syncthreads(); }
        if (t == 0) ((unsigned int*)(acc + 56))[j - 49] = su[0];
    }
}

__global__ void k_final(const float* __restrict__ acc, float* __restrict__ out) {
    if (threadIdx.x == 0 && blockIdx.x == 0) {
        const float* T = acc;
        const int* Ncnt = (const int*)(acc + 49);
        const unsigned int* m = (const unsigned int*)(acc + 56);
        float ce = 0.f;
        for (int b = 0; b < 16; b++) ce += acc[61 + b];
        ce /= (float)NN;
        unsigned long long sub  = (unsigned long long)m[0] | ((unsigned long long)m[1] << 32);
        unsigned long long intr = (unsigned long long)m[2] | ((unsigned long long)m[3] << 32);
        unsigned long long hb = sub & intr;
        float invN[NC];
        #pragma unroll
        for (int c = 0; c < NC; c++) { int n = Ncnt[c]; invN[c] = (n > 0) ? 1.f / (float)n : 0.f; }
        float lp = 0.f;
        for (int c1 = 0; c1 < NC; c1++)
            for (int c2 = 0; c2 < NC; c2++) {
                int b = c1 * 7 + c2;
                if ((hb >> b) & 1ull) lp += invN[c1] * invN[c2] * T[b];
            }
        out[0] = ce + PER_C * lp;
    }
}

// ---------------- dense fallback (ws too small), permuted-bits aware ----------------
__global__ void k_build(const int* __restrict__ adj, unsigned long long* __restrict__ bits,
                        int* __restrict__ deg, int* __restrict__ selfq) {
    int row = blockIdx.x * 4 + (threadIdx.x >> 6);
    int lane = threadIdx.x & 63;
    const int4* a4 = (const int4*)(adj + (size_t)row * NN);
    unsigned long long myw = 0ull;
    int sel = lane >> 2, sc = lane & 3;
    #pragma unroll
    for (int w4 = 0; w4 < 16; w4++) {
        int4 v = a4[w4 * 64 + lane];
        unsigned long long m0 = __ballot(v.x != 0);
        unsigned long long m1 = __ballot(v.y != 0);
        unsigned long long m2 = __ballot(v.z != 0);
        unsigned long long m3 = __ballot(v.w != 0);
        if (sel == w4) myw = (sc & 2) ? ((sc & 1) ? m3 : m2) : ((sc & 1) ? m1 : m0);
    }
    bits[(size_t)row * 64 + lane] = myw;
    int d = __popcll(myw);
    #pragma unroll
    for (int o = 32; o > 0; o >>= 1) d += __shfl_down(d, o);
    if (lane == 0) deg[row] = d;
    if (lane == (4 * (row >> 8) + (row & 3)))
        selfq[row] = (int)((myw >> ((row >> 2) & 63)) & 1ull);
}

__global__ void k_prep2(const float* __restrict__ preds, const int* __restrict__ labels,
                        const int* __restrict__ mask, float* __restrict__ diagP,
                        int* __restrict__ midx, int* __restrict__ mlab,
                        float* __restrict__ acc) {
    int t = threadIdx.x;
    if (blockIdx.x == 16) {
        __shared__ int cnts[256];
        __shared__ int sN[NC];
        if (t < 49) acc[t] = 0.f;
        if (t >= 56 && t < 60) acc[t] = 0.f;
        if (t < NC) sN[t] = 0;
        for (int i = t; i < NN; i += 256) { midx[i] = 0; mlab[i] = 0; }
        int base_n = t * 16;
        int my[16];
        int c = 0;
        #pragma unroll
        for (int k = 0; k < 16; k++) { my[k] = mask[base_n + k]; c += (my[k] != 0); }
        cnts[t] = c;
        __syncthreads();
        for (int s = 1; s < 256; s <<= 1) {
            int v = (t >= s) ? cnts[t - s] : 0;
            __syncthreads();
            cnts[t] += v;
            __syncthreads();
        }
        int pos = cnts[t] - c;
        #pragma unroll
        for (int k = 0; k < 16; k++) {
            if (my[k]) {
                int node = base_n + k;
                int l = labels[node];
                midx[pos] = node;
                mlab[pos] = l;
                atomicAdd(&sN[l], 1);
                pos++;
            }
        }
        __syncthreads();
        if (t < NC) ((int*)acc)[49 + t] = sN[t];
        if (t == 255) ((int*)acc)[60] = cnts[255];
    } else {
        int p = blockIdx.x * 256 + t;
        int l = labels[p];
        const float* pr = preds + p * NC;
        float x[NC];
        #pragma unroll
        for (int c = 0; c < NC; c++) x[c] = pr[c];
        float mx = x[0];
        #pragma unroll
        for (int c = 1; c < NC; c++) mx = fmaxf(mx, x[c]);
        float s = 0.f;
        #pragma unroll
        for (int c = 0; c < NC; c++) s += __expf(x[c] - mx);
        float lse = mx + logf(s);
        float dp = x[l];
        diagP[p] = dp;
        __shared__ float red[256];
        red[t] = lse - dp;
        __syncthreads();
        for (int st = 128; st > 0; st >>= 1) {
            if (t < st) red[t] += red[t + st];
            __syncthreads();
        }
        if (t == 0) acc[61 + blockIdx.x] = red[0];
    }
}

__launch_bounds__(256, 4)
__global__ void k_pairs(const unsigned long long* __restrict__ bits,
                        const float* __restrict__ preds,
                        const int* __restrict__ deg,
                        const float* __restrict__ diagP,
                        const int* __restrict__ selfq,
                        const int* __restrict__ midx,
                        const int* __restrict__ mlab,
                        const int* __restrict__ Mptr,
                        float* __restrict__ T,
                        unsigned int* __restrict__ g_masks) {
    __shared__ ulonglong2 lp[64 * 16];
    __shared__ ulonglong2 lq[64 * 16];
    __shared__ float predsQ[NC * 64];
    __shared__ float diagPp[64];
    __shared__ int labP[64], labQ[64], degP[64], origQ[64], sSelf[64];
    __shared__ float T_lds[49];
    __shared__ unsigned int s_m[4];

    int M = Mptr[0];
    int p0 = blockIdx.y * 64, q0 = blockIdx.x * 64;
    if (p0 >= M || q0 >= M) return;

    int t = threadIdx.x;
    if (t < 49) T_lds[t] = 0.f;
    if (t >= 49 && t < 53) s_m[t - 49] = 0u;
    if (t < 64) {
        int pi = midx[p0 + t], qi = midx[q0 + t];
        diagPp[t] = diagP[pi];
        degP[t] = deg[pi];
        labP[t] = mlab[p0 + t];
        labQ[t] = mlab[q0 + t];
        origQ[t] = qi;
        sSelf[t] = selfq[qi];
    }
    for (int idx = t; idx < NC * 64; idx += 256) {
        int c = idx >> 6, r = idx & 63;
        predsQ[idx] = preds[midx[q0 + r] * NC + c];
    }

    int tx = t & 15, ty = t >> 4;
    int cnt[4][4] = {};
    unsigned int pqbits = 0;

    for (int h = 0; h < 2; h++) {
        __syncthreads();
        #pragma unroll
        for (int i2 = 0; i2 < 4; i2++) {
            int idx = t + 256 * i2;
            int row = idx >> 4, lc = idx & 15;
            int sc = lc ^ ((row >> 2) & 7);
            lp[row * 16 + sc] = *(const ulonglong2*)&bits[(size_t)midx[p0 + row] * 64 + 32 * h + 2 * lc];
            lq[row * 16 + sc] = *(const ulonglong2*)&bits[(size_t)midx[q0 + row] * 64 + 32 * h + 2 * lc];
        }
        __syncthreads();

        const ulonglong2* Ap = lp + ty * 64;
        const ulonglong2* Bp = lq + tx * 64;
        #pragma unroll 4
        for (int c = 0; c < 16; c++) {
            int sa = c ^ (ty & 7);
            int sb = c ^ (tx & 7);
            ulonglong2 a[4], b[4];
            #pragma unroll
            for (int i = 0; i < 4; i++) a[i] = Ap[i * 16 + sa];
            #pragma unroll
            for (int j = 0; j < 4; j++) b[j] = Bp[j * 16 + sb];
            #pragma unroll
            for (int i = 0; i < 4; i++)
                #pragma unroll
                for (int j = 0; j < 4; j++)
                    cnt[i][j] += __popcll(a[i].x & b[j].x) + __popcll(a[i].y & b[j].y);
        }

        #pragma unroll
        for (int j = 0; j < 4; j++) {
            int qorig = origQ[4 * tx + j];
            int W = 4 * (qorig >> 8) + (qorig & 3);
            int chunk = W >> 1;
            if ((chunk >> 4) == h) {
                int lc = chunk & 15;
                int qh = W & 1;
                int sh = (qorig >> 2) & 63;
                #pragma unroll
                for (int i = 0; i < 4; i++) {
                    ulonglong2 cp = lp[(4 * ty + i) * 16 + (lc ^ (ty & 7))];
                    unsigned long long w = qh ? cp.y : cp.x;
                    pqbits |= ((unsigned int)((w >> sh) & 1ull)) << (i * 4 + j);
                }
            }
        }
    }

    unsigned long long lsub = 0ull, linter = 0ull;
    #pragma unroll
    for (int i = 0; i < 4; i++) {
        int pl = 4 * ty + i;
        bool pOK = (p0 + pl) < M;
        int lp_ = labP[pl], dgp = degP[pl];
        float dPp = diagPp[pl];
        #pragma unroll
        for (int j = 0; j < 4; j++) {
            int ql = 4 * tx + j;
            if (!pOK || (q0 + ql) >= M) continue;
            int inter = cnt[i][j];
            int bit_pq = (pqbits >> (i * 4 + j)) & 1;
            int sub = dgp - inter - (bit_pq & (sSelf[ql] ^ 1));
            int lq_ = labQ[ql];
            int bidx = lp_ * 7 + lq_;
            if (sub > 0)   lsub   |= 1ull << bidx;
            if (inter > 0) linter |= 1ull << bidx;
            if (lp_ != lq_) {
                float arg = (1.f + SIG1 * (float)sub) / (1.f + SIG1 * (float)inter);
                float v = 1.f / (1.f + __expf(arg));
                float E = __expf(predsQ[lp_ * 64 + ql] - dPp);
                atomicAdd(&T_lds[bidx], E * v);
            }
        }
    }
    atomicOr(&s_m[0], (unsigned int)(lsub & 0xffffffffull));
    atomicOr(&s_m[1], (unsigned int)(lsub >> 32));
    atomicOr(&s_m[2], (unsigned int)(linter & 0xffffffffull));
    atomicOr(&s_m[3], (unsigned int)(linter >> 32));
    __syncthreads();

    if (t < 49) { float v = T_lds[t]; if (v != 0.f) atomicAdd(&T[t], v); }
    if (t >= 64 && t < 68) { unsigned int m = s_m[t - 64]; if (m) atomicOr(&g_masks[t - 64], m); }
}

extern "C" void kernel_launch(void* const* d_in, const int* in_sizes, int n_in,
                              void* d_out, int out_size, void* d_ws, size_t ws_size,
                              hipStream_t stream) {
    const float* preds  = (const float*)d_in[0];
    const int*   labels = (const int*)d_in[1];
    const int*   mask   = (const int*)d_in[2];
    const int*   adj    = (const int*)d_in[3];
    float* out = (float*)d_out;

    char* ws = (char*)d_ws;
    unsigned long long* bits  = (unsigned long long*)(ws + BITS_OFF);
    int*   deg   = (int*)(ws + DEG_OFF);
    float* diagP = (float*)(ws + DIAGP_OFF);
    int*   selfq = (int*)(ws + SELF_OFF);
    int*   midx  = (int*)(ws + MIDX_OFF);
    int*   mlab  = (int*)(ws + MLAB_OFF);
    float* acc   = (float*)(ws + ACC_OFF);
    int*   minv  = (int*)(ws + MINV_OFF);
    unsigned long long* maskw = (unsigned long long*)(ws + MASKW_OFF);
    unsigned char* inter8 = (unsigned char*)(ws + INTER_OFF);
    float* partialsT = (float*)(ws + PT_OFF);
    float* T       = acc;
    const int* Mptr = (const int*)(acc + 60);
    unsigned int* g_masks = (unsigned int*)(acc + 56);

    int sparse_ok = (ws_size >= WS_NEED) ? 1 : 0;

    if (sparse_ok) {
        k_prepclear<<<PREPC_GRID, 256, 0, stream>>>(preds, labels, mask, diagP, midx, mlab,
                                                    acc, minv, maskw, (uint4*)inter8);
        k_build_scatter<<<1024, 256, 0, stream>>>(adj, deg, maskw, minv,
                                                  (unsigned int*)inter8);
        dim3 grid2(NTILE2, NTILE2);
        k_pairs2<<<grid2, 256, 0, stream>>>(preds, deg, diagP, midx, mlab,
                                            Mptr, inter8, partialsT);
        k_reduce<<<53, 256, 0, stream>>>(partialsT, acc);
        k_final<<<1, 64, 0, stream>>>(acc, out);
    } else {
        k_build<<<1024, 256, 0, stream>>>(adj, bits, deg, selfq);
        k_prep2<<<17, 256, 0, stream>>>(preds, labels, mask, diagP, midx, mlab, acc);
        dim3 grid(64, 64);
        k_pairs<<<grid, 256, 0, stream>>>(bits, preds, deg, diagP, selfq, midx, mlab,
                                          Mptr, T, g_masks);
        k_final<<<1, 64, 0, stream>>>(acc, out);
    }
}

// Round 8
// 62.770 us; speedup vs baseline: 1.5569x; 1.5569x over previous
//
#include <hip/hip_runtime.h>
#include <stdint.h>

#define NN 4096
#define NC 7
#define SIG1 0.7310585786300049f
#define PER_C 0.001f
#define ISTRIDE 2560            // >= worst-case M, multiple of 64
#define NTILE (ISTRIDE / 64)    // 40
#define NPB (NTILE * NTILE)     // 1600 tile blocks
#define CLRB 256
#define PREPC_GRID (17 + CLRB)

// ---------------- ws layout ----------------
#define BITS_OFF   0                          // u64 bits[4096][64] = 2MB (dense fallback only)
#define DEG_OFF    (2*1024*1024)              // int deg[4096]
#define DIAGP_OFF  (DEG_OFF   + NN*4)         // float diagP[4096]
#define SELF_OFF   (DIAGP_OFF + NN*4)         // int selfq[4096] (dense fallback only)
#define MIDX_OFF   (SELF_OFF  + NN*4)         // int midx[4096] (compacted masked ids)
#define MLAB_OFF   (MIDX_OFF  + NN*4)         // int mlab[4096]
#define ACC_OFF    (MLAB_OFF  + NN*4)         // 128 words; see index map below
#define MINV_OFF   (ACC_OFF   + 512)          // int minv[4096]
#define MASKW_OFF  (MINV_OFF  + NN*4)         // u64 maskw[64] (PERMUTED layout)
#define INTER_OFF  (MASKW_OFF + 512)          // u8 inter[ISTRIDE][ISTRIDE]; bit7 = adj[p,q]&~adj[q,q]
#define INTER_BYTES ((size_t)ISTRIDE * (size_t)ISTRIDE)
#define INTER_U4   ((int)(INTER_BYTES / 16))  // 409600 uint4s
#define PT_OFF     (INTER_OFF + INTER_BYTES)  // float partialsT[53][NPB]
#define PT_BYTES   ((size_t)53 * NPB * 4)
#define WS_NEED    ((size_t)PT_OFF + PT_BYTES)
// acc word indices: 0..48 T, 49..55 Ncnt(int), 56..59 masks(uint),
//                   60 M(int), 61..76 ce_part[16]

// Bit permutation: column c lives in word W(c)=4*(c>>8)+(c&3), bit b(c)=(c>>2)&63.
// Inverse: (W,b) -> c = 256*(W>>2) + 4*b + (W&3).

// Lessons encoded (r1/r2/r4/r5/r6/r7):
//  - global atomics from ~1k blocks to 5 cachelines = ~40us storm -> per-block partials.
//  - rocclr fillBuffer (hipMemsetAsync) = 40us at 8% occupancy -> clear with our own blocks.
//  - __threadfence grid handoff on gfx950 = per-XCD L2 writeback, 258us -> the kernel
//    launch boundary IS the cheap fence.
//  - 1-block reduce of 339KB cross-XCD partials = latency-bound -> 53-block reduce.
//  - scatter fused into the HBM-bound build hides; bit7 written by the COLUMN wave.
//  - 128x128 pair tile -> 1 block/CU, LDS atomics latency fully exposed (54us, occ 7%)
//    -> keep 64x64 (1024 active blocks, ~16 waves/CU) + reduce atomics via shuffles.

// ---------------- sparse path ----------------

// k_prepclear: blocks 0..15 CE partials + diagP; block 16: acc zero, compact scan,
// Ncnt, M, minv, permuted maskw; blocks 17..272: clear inter8.
__global__ void k_prepclear(const float* __restrict__ preds, const int* __restrict__ labels,
                            const int* __restrict__ mask, float* __restrict__ diagP,
                            int* __restrict__ midx, int* __restrict__ mlab,
                            float* __restrict__ acc, int* __restrict__ minv,
                            unsigned long long* __restrict__ maskw,
                            uint4* __restrict__ inter_clear) {
    int t = threadIdx.x;
    int b = blockIdx.x;
    if (b >= 17) {
        int cb = b - 17;                       // 0..CLRB-1
        for (int i = cb * 256 + t; i < INTER_U4; i += CLRB * 256)
            inter_clear[i] = make_uint4(0u, 0u, 0u, 0u);
        return;
    }
    if (b == 16) {
        __shared__ int cnts[256];
        __shared__ int sN[NC];
        if (t < 49) acc[t] = 0.f;                 // T
        if (t >= 56 && t < 60) acc[t] = 0.f;      // masks
        if (t < NC) sN[t] = 0;
        for (int i = t; i < NN; i += 256) { midx[i] = 0; mlab[i] = 0; }
        if (t < 64) {
            // permuted: maskw[W] bit b = mask[256*(W>>2) + 4*b + (W&3)]
            int base = 256 * (t >> 2) + (t & 3);
            unsigned long long w = 0ull;
            for (int bb = 0; bb < 64; bb++)
                w |= ((unsigned long long)(mask[base + 4 * bb] != 0)) << bb;
            maskw[t] = w;
        }

        int base_n = t * 16;
        int my[16];
        int c = 0;
        #pragma unroll
        for (int k = 0; k < 16; k++) { my[k] = mask[base_n + k]; c += (my[k] != 0); }
        cnts[t] = c;
        __syncthreads();
        for (int s = 1; s < 256; s <<= 1) {
            int v = (t >= s) ? cnts[t - s] : 0;
            __syncthreads();
            cnts[t] += v;
            __syncthreads();
        }
        int pos = cnts[t] - c;  // exclusive prefix
        #pragma unroll
        for (int k = 0; k < 16; k++) {
            if (my[k]) {
                int node = base_n + k;
                int l = labels[node];
                midx[pos] = node;
                mlab[pos] = l;
                minv[node] = pos;
                atomicAdd(&sN[l], 1);
                pos++;
            }
        }
        __syncthreads();
        if (t < NC) ((int*)acc)[49 + t] = sN[t];
        if (t == 255) ((int*)acc)[60] = cnts[255];   // M
    } else {
        int p = b * 256 + t;
        int l = labels[p];
        const float* pr = preds + p * NC;
        float x[NC];
        #pragma unroll
        for (int c = 0; c < NC; c++) x[c] = pr[c];
        float mx = x[0];
        #pragma unroll
        for (int c = 1; c < NC; c++) mx = fmaxf(mx, x[c]);
        float s = 0.f;
        #pragma unroll
        for (int c = 0; c < NC; c++) s += __expf(x[c] - mx);
        float lse = mx + logf(s);
        float dp = x[l];
        diagP[p] = dp;

        __shared__ float red[256];
        red[t] = lse - dp;
        __syncthreads();
        for (int st = 128; st > 0; st >>= 1) {
            if (t < st) red[t] += red[t + st];
            __syncthreads();
        }
        if (t == 0) acc[61 + b] = red[0];
    }
}

// k_build_scatter: one wave per row k. Streams the 64MB adj row (int4, permuted
// ballots), writes deg, then (row still in regs) scatters:
//  - inter[i][j] += 1 for each pair (i,j) of MASKED neighbors of k (low 7 bits)
//  - if k masked AND adj[k,k]==0: bit7 of inter[minv[p]][minv[k]] for each masked
//    neighbor p (column-flip: writer owns its own diagonal bit in registers).
__global__ void k_build_scatter(const int* __restrict__ adj,
                                int* __restrict__ deg,
                                const unsigned long long* __restrict__ maskw,
                                const int* __restrict__ minv,
                                unsigned int* __restrict__ inter32) {
    __shared__ unsigned short L[4][80];
    __shared__ int sn[4];
    int w = threadIdx.x >> 6, lane = threadIdx.x & 63;
    int row = blockIdx.x * 4 + w;
    const int4* a4 = (const int4*)(adj + (size_t)row * NN);
    unsigned long long myw = 0ull;
    int sel = lane >> 2, sc = lane & 3;
    #pragma unroll
    for (int w4 = 0; w4 < 16; w4++) {
        int4 v = a4[w4 * 64 + lane];   // cols 256*w4 + 4*lane + {0..3}; 1KB/instr coalesced
        unsigned long long m0 = __ballot(v.x != 0);
        unsigned long long m1 = __ballot(v.y != 0);
        unsigned long long m2 = __ballot(v.z != 0);
        unsigned long long m3 = __ballot(v.w != 0);
        if (sel == w4) myw = (sc & 2) ? ((sc & 1) ? m3 : m2) : ((sc & 1) ? m1 : m0);
    }
    int d = __popcll(myw);
    #pragma unroll
    for (int o = 32; o > 0; o >>= 1) d += __shfl_down(d, o);
    if (lane == 0) deg[row] = d;

    // ---- fused scatter ----
    unsigned long long bw = myw & maskw[lane];
    int c = __popcll(bw);
    int inc = c;
    #pragma unroll
    for (int o = 1; o < 64; o <<= 1) { int v = __shfl_up(inc, o); if (lane >= o) inc += v; }
    int pos = inc - c;                 // exclusive prefix
    unsigned long long tmp = bw;
    while (tmp) {
        int bb = __ffsll(tmp) - 1;
        tmp &= tmp - 1;
        int node = 256 * (lane >> 2) + 4 * bb + (lane & 3);   // permuted decode
        if (pos < 80) L[w][pos] = (unsigned short)minv[node];
        pos++;
    }
    if (lane == 63) sn[w] = (inc < 80) ? inc : 80;
    __syncthreads();

    int n = sn[w];
    for (int idx = lane; idx < n * n; idx += 64) {
        int i = idx / n, j = idx - i * n;
        unsigned int a = (unsigned int)L[w][i] * ISTRIDE + (unsigned int)L[w][j];
        atomicAdd(&inter32[a >> 2], 1u << ((a & 3) * 8));
    }

    // column-flip bit7: row k (= column q) masked and own diagonal == 0
    int Wk = 4 * (row >> 8) + (row & 3);
    int km = (int)((maskw[Wk] >> ((row >> 2) & 63)) & 1ull);
    if (km) {
        unsigned long long dw = __shfl(myw, Wk);
        int selfk = (int)((dw >> ((row >> 2) & 63)) & 1ull);
        if (!selfk) {
            int kc = minv[row];
            for (int j = lane; j < n; j += 64) {
                unsigned int a = (unsigned int)L[w][j] * ISTRIDE + (unsigned int)kc;
                atomicOr(&inter32[a >> 2], 0x80u << ((a & 3) * 8));
            }
        }
    }
}

// Pair epilogue: 64x64 tile, 4x4 per thread, 1600 blocks (1024 active -> ~16
// waves/CU of TLP). Per p-row, lp_ is uniform across the 16 tx lanes: accumulate
// E*v into a 7-register class array (branchless selects, static indexing), then
// 4-step shfl_xor reduce over the aligned 16-lane tx group; only tx==0 issues <=7
// LDS atomics per row (~9x fewer LDS atomics than per-pair). All lanes stay
// converged (predication, no continue) so the shuffles are well-defined.
__launch_bounds__(256)
__global__ void k_pairs2(const float* __restrict__ preds,
                         const int* __restrict__ deg,
                         const float* __restrict__ diagP,
                         const int* __restrict__ midx,
                         const int* __restrict__ mlab,
                         const int* __restrict__ Mptr,
                         const unsigned char* __restrict__ inter8,
                         float* __restrict__ partialsT) {
    __shared__ float predsQ[NC * 64];   // transposed [c][r]
    __shared__ float diagPp[64];
    __shared__ int labP[64], labQ[64], degP[64];
    __shared__ float T_lds[49];
    __shared__ unsigned int s_m[4];

    int M = Mptr[0];
    int p0 = blockIdx.y * 64, q0 = blockIdx.x * 64;
    int bl = blockIdx.y * gridDim.x + blockIdx.x;   // 0..NPB-1
    int t = threadIdx.x;

    if (p0 >= M || q0 >= M) {
        if (t < 53) partialsT[t * NPB + bl] = 0.f;
        return;
    }

    if (t < 49) T_lds[t] = 0.f;
    if (t >= 49 && t < 53) s_m[t - 49] = 0u;
    if (t < 64) {
        int pi = midx[p0 + t];
        diagPp[t] = diagP[pi];
        degP[t] = deg[pi];
        labP[t] = mlab[p0 + t];
        labQ[t] = mlab[q0 + t];
    }
    for (int idx = t; idx < NC * 64; idx += 256) {
        int c = idx >> 6, r = idx & 63;
        predsQ[idx] = preds[midx[q0 + r] * NC + c];
    }
    __syncthreads();

    int tx = t & 15, ty = t >> 4;
    int lane = t & 63;
    unsigned long long lsub = 0ull, linter = 0ull;

    #pragma unroll
    for (int i = 0; i < 4; i++) {
        int pl = 4 * ty + i;
        bool pOK = (p0 + pl) < M;
        int lp_ = labP[pl], dgp = degP[pl];
        float dPp = diagPp[pl];
        unsigned int iw = *(const unsigned int*)&inter8[(size_t)(p0 + pl) * ISTRIDE + q0 + 4 * tx];
        float a7[7] = {0.f, 0.f, 0.f, 0.f, 0.f, 0.f, 0.f};
        #pragma unroll
        for (int j = 0; j < 4; j++) {
            int ql = 4 * tx + j;
            bool ok = pOK && ((q0 + ql) < M);
            unsigned int u = (iw >> (8 * j)) & 255u;
            int inter = (int)(u & 127u);
            int bitterm = (int)(u >> 7);
            int sub = dgp - inter - bitterm;
            int lq_ = labQ[ql];
            int bidx = lp_ * 7 + lq_;
            if (ok && sub > 0)   lsub   |= 1ull << bidx;
            if (ok && inter > 0) linter |= 1ull << bidx;
            float arg = (1.f + SIG1 * (float)sub) / (1.f + SIG1 * (float)inter);
            float v = 1.f / (1.f + __expf(arg));            // 1 - sigmoid(arg)
            float E = __expf(predsQ[lp_ * 64 + ql] - dPp);  // exp(G - diagP)
            float ev = (ok && (lp_ != lq_)) ? E * v : 0.f;
            #pragma unroll
            for (int c = 0; c < 7; c++) a7[c] += (lq_ == c) ? ev : 0.f;
        }
        // reduce across the aligned, branch-uniform 16-lane tx group
        #pragma unroll
        for (int c = 0; c < 7; c++) {
            float s = a7[c];
            s += __shfl_xor(s, 1);
            s += __shfl_xor(s, 2);
            s += __shfl_xor(s, 4);
            s += __shfl_xor(s, 8);
            if (tx == 0 && s != 0.f) atomicAdd(&T_lds[lp_ * 7 + c], s);
        }
    }
    // wave-level OR reduce, then 4 LDS atomics per wave
    #pragma unroll
    for (int o = 32; o > 0; o >>= 1) {
        lsub   |= __shfl_xor(lsub, o);
        linter |= __shfl_xor(linter, o);
    }
    if (lane == 0) {
        atomicOr(&s_m[0], (unsigned int)(lsub & 0xffffffffull));
        atomicOr(&s_m[1], (unsigned int)(lsub >> 32));
        atomicOr(&s_m[2], (unsigned int)(linter & 0xffffffffull));
        atomicOr(&s_m[3], (unsigned int)(linter >> 32));
    }
    __syncthreads();

    if (t < 49) partialsT[t * NPB + bl] = T_lds[t];
    if (t >= 49 && t < 53) partialsT[t * NPB + bl] = __uint_as_float(s_m[t - 49]);
}

// Reduce partialsT[53][NPB] -> acc. 53 blocks (parallel; 1-block variant was
// latency-bound, r5). j<49: float sum; j>=49: OR into masks.
__global__ void k_reduce(const float* __restrict__ pt, float* __restrict__ acc) {
    int j = blockIdx.x;      // 0..52
    int t = threadIdx.x;     // 256
    const float* row = pt + (size_t)j * NPB;
    if (j < 49) {
        __shared__ float sf[256];
        float s = 0.f;
        for (int i = t; i < NPB; i += 256) s += row[i];
        sf[t] = s;
        __syncthreads();
        for (int st = 128; st > 0; st >>= 1) { if (t < st) sf[t] += sf[t + st]; __syncthreads(); }
        if (t == 0) acc[j] = sf[0];
    } else {
        __shared__ unsigned int su[256];
        unsigned int m = 0u;
        for (int i = t; i < NPB; i += 256) m |= __float_as_uint(row[i]);
        su[t] = m;
        __syncthreads();
        for (int st = 128; st > 0; st >>= 1) { if (t < st) su[t] |= su[t + st]; __syncthreads(); }
        if (t == 0) ((unsigned int*)(acc + 56))[j - 49] = su[0];
    }
}

__global__ void k_final(const float* __restrict__ acc, float* __restrict__ out) {
    if (threadIdx.x == 0 && blockIdx.x == 0) {
        const float* T = acc;
        const int* Ncnt = (const int*)(acc + 49);
        const unsigned int* m = (const unsigned int*)(acc + 56);
        float ce = 0.f;
        for (int b = 0; b < 16; b++) ce += acc[61 + b];
        ce /= (float)NN;
        unsigned long long sub  = (unsigned long long)m[0] | ((unsigned long long)m[1] << 32);
        unsigned long long intr = (unsigned long long)m[2] | ((unsigned long long)m[3] << 32);
        unsigned long long hb = sub & intr;
        float invN[NC];
        #pragma unroll
        for (int c = 0; c < NC; c++) { int n = Ncnt[c]; invN[c] = (n > 0) ? 1.f / (float)n : 0.f; }
        float lp = 0.f;
        for (int c1 = 0; c1 < NC; c1++)
            for (int c2 = 0; c2 < NC; c2++) {
                int b = c1 * 7 + c2;
                if ((hb >> b) & 1ull) lp += invN[c1] * invN[c2] * T[b];
            }
        out[0] = ce + PER_C * lp;
    }
}

// ---------------- dense fallback (ws too small), permuted-bits aware ----------------
__global__ void k_build(const int* __restrict__ adj, unsigned long long* __restrict__ bits,
                        int* __restrict__ deg, int* __restrict__ selfq) {
    int row = blockIdx.x * 4 + (threadIdx.x >> 6);
    int lane = threadIdx.x & 63;
    const int4* a4 = (const int4*)(adj + (size_t)row * NN);
    unsigned long long myw = 0ull;
    int sel = lane >> 2, sc = lane & 3;
    #pragma unroll
    for (int w4 = 0; w4 < 16; w4++) {
        int4 v = a4[w4 * 64 + lane];
        unsigned long long m0 = __ballot(v.x != 0);
        unsigned long long m1 = __ballot(v.y != 0);
        unsigned long long m2 = __ballot(v.z != 0);
        unsigned long long m3 = __ballot(v.w != 0);
        if (sel == w4) myw = (sc & 2) ? ((sc & 1) ? m3 : m2) : ((sc & 1) ? m1 : m0);
    }
    bits[(size_t)row * 64 + lane] = myw;
    int d = __popcll(myw);
    #pragma unroll
    for (int o = 32; o > 0; o >>= 1) d += __shfl_down(d, o);
    if (lane == 0) deg[row] = d;
    if (lane == (4 * (row >> 8) + (row & 3)))
        selfq[row] = (int)((myw >> ((row >> 2) & 63)) & 1ull);
}

__global__ void k_prep2(const float* __restrict__ preds, const int* __restrict__ labels,
                        const int* __restrict__ mask, float* __restrict__ diagP,
                        int* __restrict__ midx, int* __restrict__ mlab,
                        float* __restrict__ acc) {
    int t = threadIdx.x;
    if (blockIdx.x == 16) {
        __shared__ int cnts[256];
        __shared__ int sN[NC];
        if (t < 49) acc[t] = 0.f;
        if (t >= 56 && t < 60) acc[t] = 0.f;
        if (t < NC) sN[t] = 0;
        for (int i = t; i < NN; i += 256) { midx[i] = 0; mlab[i] = 0; }
        int base_n = t * 16;
        int my[16];
        int c = 0;
        #pragma unroll
        for (int k = 0; k < 16; k++) { my[k] = mask[base_n + k]; c += (my[k] != 0); }
        cnts[t] = c;
        __syncthreads();
        for (int s = 1; s < 256; s <<= 1) {
            int v = (t >= s) ? cnts[t - s] : 0;
            __syncthreads();
            cnts[t] += v;
            __syncthreads();
        }
        int pos = cnts[t] - c;
        #pragma unroll
        for (int k = 0; k < 16; k++) {
            if (my[k]) {
                int node = base_n + k;
                int l = labels[node];
                midx[pos] = node;
                mlab[pos] = l;
                atomicAdd(&sN[l], 1);
                pos++;
            }
        }
        __syncthreads();
        if (t < NC) ((int*)acc)[49 + t] = sN[t];
        if (t == 255) ((int*)acc)[60] = cnts[255];
    } else {
        int p = blockIdx.x * 256 + t;
        int l = labels[p];
        const float* pr = preds + p * NC;
        float x[NC];
        #pragma unroll
        for (int c = 0; c < NC; c++) x[c] = pr[c];
        float mx = x[0];
        #pragma unroll
        for (int c = 1; c < NC; c++) mx = fmaxf(mx, x[c]);
        float s = 0.f;
        #pragma unroll
        for (int c = 0; c < NC; c++) s += __expf(x[c] - mx);
        float lse = mx + logf(s);
        float dp = x[l];
        diagP[p] = dp;
        __shared__ float red[256];
        red[t] = lse - dp;
        __syncthreads();
        for (int st = 128; st > 0; st >>= 1) {
            if (t < st) red[t] += red[t + st];
            __syncthreads();
        }
        if (t == 0) acc[61 + blockIdx.x] = red[0];
    }
}

__launch_bounds__(256, 4)
__global__ void k_pairs(const unsigned long long* __restrict__ bits,
                        const float* __restrict__ preds,
                        const int* __restrict__ deg,
                        const float* __restrict__ diagP,
                        const int* __restrict__ selfq,
                        const int* __restrict__ midx,
                        const int* __restrict__ mlab,
                        const int* __restrict__ Mptr,
                        float* __restrict__ T,
                        unsigned int* __restrict__ g_masks) {
    __shared__ ulonglong2 lp[64 * 16];
    __shared__ ulonglong2 lq[64 * 16];
    __shared__ float predsQ[NC * 64];
    __shared__ float diagPp[64];
    __shared__ int labP[64], labQ[64], degP[64], origQ[64], sSelf[64];
    __shared__ float T_lds[49];
    __shared__ unsigned int s_m[4];

    int M = Mptr[0];
    int p0 = blockIdx.y * 64, q0 = blockIdx.x * 64;
    if (p0 >= M || q0 >= M) return;

    int t = threadIdx.x;
    if (t < 49) T_lds[t] = 0.f;
    if (t >= 49 && t < 53) s_m[t - 49] = 0u;
    if (t < 64) {
        int pi = midx[p0 + t], qi = midx[q0 + t];
        diagPp[t] = diagP[pi];
        degP[t] = deg[pi];
        labP[t] = mlab[p0 + t];
        labQ[t] = mlab[q0 + t];
        origQ[t] = qi;
        sSelf[t] = selfq[qi];
    }
    for (int idx = t; idx < NC * 64; idx += 256) {
        int c = idx >> 6, r = idx & 63;
        predsQ[idx] = preds[midx[q0 + r] * NC + c];
    }

    int tx = t & 15, ty = t >> 4;
    int cnt[4][4] = {};
    unsigned int pqbits = 0;

    for (int h = 0; h < 2; h++) {
        __syncthreads();
        #pragma unroll
        for (int i2 = 0; i2 < 4; i2++) {
            int idx = t + 256 * i2;
            int row = idx >> 4, lc = idx & 15;
            int sc = lc ^ ((row >> 2) & 7);
            lp[row * 16 + sc] = *(const ulonglong2*)&bits[(size_t)midx[p0 + row] * 64 + 32 * h + 2 * lc];
            lq[row * 16 + sc] = *(const ulonglong2*)&bits[(size_t)midx[q0 + row] * 64 + 32 * h + 2 * lc];
        }
        __syncthreads();

        const ulonglong2* Ap = lp + ty * 64;
        const ulonglong2* Bp = lq + tx * 64;
        #pragma unroll 4
        for (int c = 0; c < 16; c++) {
            int sa = c ^ (ty & 7);
            int sb = c ^ (tx & 7);
            ulonglong2 a[4], b[4];
            #pragma unroll
            for (int i = 0; i < 4; i++) a[i] = Ap[i * 16 + sa];
            #pragma unroll
            for (int j = 0; j < 4; j++) b[j] = Bp[j * 16 + sb];
            #pragma unroll
            for (int i = 0; i < 4; i++)
                #pragma unroll
                for (int j = 0; j < 4; j++)
                    cnt[i][j] += __popcll(a[i].x & b[j].x) + __popcll(a[i].y & b[j].y);
        }

        #pragma unroll
        for (int j = 0; j < 4; j++) {
            int qorig = origQ[4 * tx + j];
            int W = 4 * (qorig >> 8) + (qorig & 3);
            int chunk = W >> 1;
            if ((chunk >> 4) == h) {
                int lc = chunk & 15;
                int qh = W & 1;
                int sh = (qorig >> 2) & 63;
                #pragma unroll
                for (int i = 0; i < 4; i++) {
                    ulonglong2 cp = lp[(4 * ty + i) * 16 + (lc ^ (ty & 7))];
                    unsigned long long w = qh ? cp.y : cp.x;
                    pqbits |= ((unsigned int)((w >> sh) & 1ull)) << (i * 4 + j);
                }
            }
        }
    }

    unsigned long long lsub = 0ull, linter = 0ull;
    #pragma unroll
    for (int i = 0; i < 4; i++) {
        int pl = 4 * ty + i;
        bool pOK = (p0 + pl) < M;
        int lp_ = labP[pl], dgp = degP[pl];
        float dPp = diagPp[pl];
        #pragma unroll
        for (int j = 0; j < 4; j++) {
            int ql = 4 * tx + j;
            if (!pOK || (q0 + ql) >= M) continue;
            int inter = cnt[i][j];
            int bit_pq = (pqbits >> (i * 4 + j)) & 1;
            int sub = dgp - inter - (bit_pq & (sSelf[ql] ^ 1));
            int lq_ = labQ[ql];
            int bidx = lp_ * 7 + lq_;
            if (sub > 0)   lsub   |= 1ull << bidx;
            if (inter > 0) linter |= 1ull << bidx;
            if (lp_ != lq_) {
                float arg = (1.f + SIG1 * (float)sub) / (1.f + SIG1 * (float)inter);
                float v = 1.f / (1.f + __expf(arg));
                float E = __expf(predsQ[lp_ * 64 + ql] - dPp);
                atomicAdd(&T_lds[bidx], E * v);
            }
        }
    }
    atomicOr(&s_m[0], (unsigned int)(lsub & 0xffffffffull));
    atomicOr(&s_m[1], (unsigned int)(lsub >> 32));
    atomicOr(&s_m[2], (unsigned int)(linter & 0xffffffffull));
    atomicOr(&s_m[3], (unsigned int)(linter >> 32));
    __syncthreads();

    if (t < 49) { float v = T_lds[t]; if (v != 0.f) atomicAdd(&T[t], v); }
    if (t >= 64 && t < 68) { unsigned int m = s_m[t - 64]; if (m) atomicOr(&g_masks[t - 64], m); }
}

extern "C" void kernel_launch(void* const* d_in, const int* in_sizes, int n_in,
                              void* d_out, int out_size, void* d_ws, size_t ws_size,
                              hipStream_t stream) {
    const float* preds  = (const float*)d_in[0];
    const int*   labels = (const int*)d_in[1];
    const int*   mask   = (const int*)d_in[2];
    const int*   adj    = (const int*)d_in[3];
    float* out = (float*)d_out;

    char* ws = (char*)d_ws;
    unsigned long long* bits  = (unsigned long long*)(ws + BITS_OFF);
    int*   deg   = (int*)(ws + DEG_OFF);
    float* diagP = (float*)(ws + DIAGP_OFF);
    int*   selfq = (int*)(ws + SELF_OFF);
    int*   midx  = (int*)(ws + MIDX_OFF);
    int*   mlab  = (int*)(ws + MLAB_OFF);
    float* acc   = (float*)(ws + ACC_OFF);
    int*   minv  = (int*)(ws + MINV_OFF);
    unsigned long long* maskw = (unsigned long long*)(ws + MASKW_OFF);
    unsigned char* inter8 = (unsigned char*)(ws + INTER_OFF);
    float* partialsT = (float*)(ws + PT_OFF);
    float* T       = acc;
    const int* Mptr = (const int*)(acc + 60);
    unsigned int* g_masks = (unsigned int*)(acc + 56);

    int sparse_ok = (ws_size >= WS_NEED) ? 1 : 0;

    if (sparse_ok) {
        k_prepclear<<<PREPC_GRID, 256, 0, stream>>>(preds, labels, mask, diagP, midx, mlab,
                                                    acc, minv, maskw, (uint4*)inter8);
        k_build_scatter<<<1024, 256, 0, stream>>>(adj, deg, maskw, minv,
                                                  (unsigned int*)inter8);
        dim3 grid2(NTILE, NTILE);
        k_pairs2<<<grid2, 256, 0, stream>>>(preds, deg, diagP, midx, mlab,
                                            Mptr, inter8, partialsT);
        k_reduce<<<53, 256, 0, stream>>>(partialsT, acc);
        k_final<<<1, 64, 0, stream>>>(acc, out);
    } else {
        k_build<<<1024, 256, 0, stream>>>(adj, bits, deg, selfq);
        k_prep2<<<17, 256, 0, stream>>>(preds, labels, mask, diagP, midx, mlab, acc);
        dim3 grid(64, 64);
        k_pairs<<<grid, 256, 0, stream>>>(bits, preds, deg, diagP, selfq, midx, mlab,
                                          Mptr, T, g_masks);
        k_final<<<1, 64, 0, stream>>>(acc, out);
    }
}